// Round 1
// baseline (45635.175 us; speedup 1.0000x reference)
//
#include <hip/hip_runtime.h>
#include <hip/hip_bf16.h>

#define N_D 256

typedef __attribute__((ext_vector_type(8))) short bf16x8;
typedef __attribute__((ext_vector_type(4))) float f32x4;

// f32 -> bf16 round-to-nearest-even (finite inputs)
__device__ __forceinline__ short f2bf(float f) {
  union { float f; unsigned u; } c; c.f = f;
  unsigned u = c.u;
  unsigned r = (u + 0x7fffu + ((u >> 16) & 1u)) >> 16;
  return (short)r;
}

// out[rows[e], :] += 0.5 * vals[e] * h[cols[e], :]
// One wave (64 lanes) per edge; lane handles 4 consecutive floats (float4).
__global__ __launch_bounds__(256) void spmm_atomic(
    const float* __restrict__ h, const float* __restrict__ vals,
    const int* __restrict__ rows, const int* __restrict__ cols,
    float* __restrict__ out, int n_edges) {
  int gid = blockIdx.x * 256 + threadIdx.x;
  int edge = gid >> 6;            // wave-uniform
  int lane = threadIdx.x & 63;
  if (edge >= n_edges) return;
  int r = rows[edge];
  int c = cols[edge];
  float v = vals[edge] * 0.5f;    // fold FACTOR into the edge weight
  const float4* src = reinterpret_cast<const float4*>(h + (size_t)c * N_D);
  float4 d = src[lane];
  float* dst = out + (size_t)r * N_D + (size_t)lane * 4;
  unsafeAtomicAdd(dst + 0, v * d.x);
  unsafeAtomicAdd(dst + 1, v * d.y);
  unsafeAtomicAdd(dst + 2, v * d.z);
  unsafeAtomicAdd(dst + 3, v * d.w);
}

// C[M,256] = act(H[M,256] @ W[256,256]); bf16 MFMA 16x16x32, fp32 accum.
// Block: 256 threads = 4 waves. Wave w: rows [bx*64 + w*16, +16), cols [by*64, +64).
template <bool RELU>
__global__ __launch_bounds__(256) void gemm_kernel(
    const float* __restrict__ H, const float* __restrict__ W,
    float* __restrict__ C, int M) {
  const int wave = threadIdx.x >> 6;
  const int lane = threadIdx.x & 63;
  const int row0 = blockIdx.x * 64 + wave * 16;
  const int col0 = blockIdx.y * 64;
  const int m = lane & 15;   // A row within tile; also C col within 16-col tile
  const int p = lane >> 4;   // k-block (0..3)

  f32x4 acc[4];
#pragma unroll
  for (int i = 0; i < 4; ++i) acc[i] = (f32x4){0.f, 0.f, 0.f, 0.f};

  const int row = row0 + m;
  const bool rowok = row < M;
  const float* hrow = H + (size_t)row * N_D;

  for (int k0 = 0; k0 < N_D; k0 += 32) {
    // A fragment: A[row][k0 + p*8 + j], j=0..7 (32B contiguous per lane)
    bf16x8 a = {0, 0, 0, 0, 0, 0, 0, 0};
    if (rowok) {
      const float* srcA = hrow + k0 + p * 8;
#pragma unroll
      for (int j = 0; j < 8; ++j) a[j] = f2bf(srcA[j]);
    }
#pragma unroll
    for (int nt = 0; nt < 4; ++nt) {
      // B fragment: W[k0 + p*8 + j][col0 + nt*16 + m] (same k-mapping as A)
      const float* srcB = W + (size_t)(k0 + p * 8) * N_D + col0 + nt * 16 + m;
      bf16x8 b;
#pragma unroll
      for (int j = 0; j < 8; ++j) b[j] = f2bf(srcB[(size_t)j * N_D]);
      acc[nt] = __builtin_amdgcn_mfma_f32_16x16x32_bf16(a, b, acc[nt], 0, 0, 0);
    }
  }

  // C/D layout (HW-verified): col = lane&15, row = (lane>>4)*4 + reg
  const int orow = row0 + p * 4;
#pragma unroll
  for (int nt = 0; nt < 4; ++nt) {
    const int col = col0 + nt * 16 + m;
#pragma unroll
    for (int rr = 0; rr < 4; ++rr) {
      const int r = orow + rr;
      if (r < M) {
        float vv = acc[nt][rr];
        if (RELU) vv = fmaxf(vv, 0.f);
        C[(size_t)r * N_D + col] = vv;
      }
    }
  }
}

extern "C" void kernel_launch(void* const* d_in, const int* in_sizes, int n_in,
                              void* d_out, int out_size, void* d_ws, size_t ws_size,
                              hipStream_t stream) {
  const float* x    = (const float*)d_in[0];
  const float* vals = (const float*)d_in[1];
  const float* W0   = (const float*)d_in[2];
  const float* W1   = (const float*)d_in[3];
  const int*   rows = (const int*)d_in[4];
  const int*   cols = (const int*)d_in[5];

  const int n_edges = in_sizes[1];
  const int M = in_sizes[0] / N_D;               // 100000 nodes
  const size_t hbytes = (size_t)M * N_D * sizeof(float);

  float* out = (float*)d_out;
  float* wsA = (float*)d_ws;                     // needs 102.4 MB

  const int spmm_blocks = (n_edges + 3) / 4;     // 4 waves (edges) per 256-thr block
  dim3 ggrid((M + 63) / 64, 4);

  // 1: wsA = spmm(x) * 0.5
  hipMemsetAsync(wsA, 0, hbytes, stream);
  spmm_atomic<<<spmm_blocks, 256, 0, stream>>>(x, vals, rows, cols, wsA, n_edges);
  // 2: out = spmm(wsA) * 0.5
  hipMemsetAsync(out, 0, hbytes, stream);
  spmm_atomic<<<spmm_blocks, 256, 0, stream>>>(wsA, vals, rows, cols, out, n_edges);
  // 3: wsA = relu(out @ W0)
  gemm_kernel<true><<<ggrid, 256, 0, stream>>>(out, W0, wsA, M);
  // 4: out = spmm(wsA) * 0.5
  hipMemsetAsync(out, 0, hbytes, stream);
  spmm_atomic<<<spmm_blocks, 256, 0, stream>>>(wsA, vals, rows, cols, out, n_edges);
  // 5: wsA = spmm(out) * 0.5
  hipMemsetAsync(wsA, 0, hbytes, stream);
  spmm_atomic<<<spmm_blocks, 256, 0, stream>>>(out, vals, rows, cols, wsA, n_edges);
  // 6: out = wsA @ W1
  gemm_kernel<false><<<ggrid, 256, 0, stream>>>(wsA, W1, out, M);
}

// Round 2
// 1743.382 us; speedup vs baseline: 26.1762x; 26.1762x over previous
//
#include <hip/hip_runtime.h>
#include <hip/hip_bf16.h>

#define N_D 256

typedef __attribute__((ext_vector_type(8))) short bf16x8;
typedef __attribute__((ext_vector_type(4))) float f32x4;

// f32 -> bf16 round-to-nearest-even (finite inputs)
__device__ __forceinline__ unsigned short f2bf(float f) {
  union { float f; unsigned u; } c; c.f = f;
  unsigned u = c.u;
  return (unsigned short)((u + 0x7fffu + ((u >> 16) & 1u)) >> 16);
}
__device__ __forceinline__ float bf2f(unsigned short u) {
  union { unsigned u; float f; } c; c.u = ((unsigned)u) << 16;
  return c.f;
}

// ---------- CSR build ----------
__global__ __launch_bounds__(256) void hist_kernel(
    const int* __restrict__ rows, int* __restrict__ cnt, int n_edges) {
  int e = blockIdx.x * 256 + threadIdx.x;
  if (e < n_edges) atomicAdd(&cnt[rows[e]], 1);
}

// exclusive scan of cnt[0..n) -> row_ptr[0..n], single block of 1024
__global__ __launch_bounds__(1024) void scan_kernel(
    const int* __restrict__ cnt, int* __restrict__ row_ptr, int n) {
  __shared__ int sh[1024];
  __shared__ int carry_sh;
  const int tid = threadIdx.x;
  if (tid == 0) carry_sh = 0;
  __syncthreads();
  for (int base = 0; base < n; base += 1024) {
    int i = base + tid;
    int v = (i < n) ? cnt[i] : 0;
    int sum = v;
    sh[tid] = sum;
    __syncthreads();
#pragma unroll
    for (int off = 1; off < 1024; off <<= 1) {
      int prev = (tid >= off) ? sh[tid - off] : 0;
      __syncthreads();
      sum += prev;
      sh[tid] = sum;
      __syncthreads();
    }
    int carry = carry_sh;
    if (i < n) row_ptr[i] = carry + sum - v;   // exclusive
    __syncthreads();                           // everyone read carry_sh
    if (tid == 1023) carry_sh = carry + sum;
    __syncthreads();
  }
  if (tid == 0) row_ptr[n] = carry_sh;
}

// colval[pos] = (col, 0.5*val) grouped by destination row
__global__ __launch_bounds__(256) void scatter_kernel(
    const int* __restrict__ rows, const int* __restrict__ cols,
    const float* __restrict__ vals, int* __restrict__ cursor,
    int2* __restrict__ colval, int n_edges) {
  int e = blockIdx.x * 256 + threadIdx.x;
  if (e < n_edges) {
    int r = rows[e];
    int pos = atomicAdd(&cursor[r], 1);
    int2 cv;
    cv.x = cols[e];
    union { float f; int i; } c; c.f = vals[e] * 0.5f;
    cv.y = c.i;
    colval[pos] = cv;
  }
}

// ---------- SpMM: one wave per destination node, gather + register accum ----------
template <bool F32IN>
__global__ __launch_bounds__(256) void spmm_csr(
    const void* __restrict__ hin, const int* __restrict__ row_ptr,
    const int2* __restrict__ colval, unsigned short* __restrict__ hout,
    int n_nodes) {
  const int node = (blockIdx.x * 256 + threadIdx.x) >> 6;  // wave-uniform
  const int lane = threadIdx.x & 63;
  if (node >= n_nodes) return;
  const int start = row_ptr[node];
  const int end   = row_ptr[node + 1];

  float a0 = 0.f, a1 = 0.f, a2 = 0.f, a3 = 0.f;

  for (int base = start; base < end; base += 64) {
    const int cnt = min(64, end - base);
    int2 cv = make_int2(0, 0);
    if (base + lane < end) cv = colval[base + lane];
    for (int t = 0; t < cnt; ++t) {
      int c = __builtin_amdgcn_readlane(cv.x, t);
      union { int i; float f; } vv; vv.i = __builtin_amdgcn_readlane(cv.y, t);
      float v = vv.f;
      if (F32IN) {
        const float4 hv = reinterpret_cast<const float4*>(hin)[(size_t)c * 64 + lane];
        a0 += v * hv.x; a1 += v * hv.y; a2 += v * hv.z; a3 += v * hv.w;
      } else {
        const ushort4 hv = reinterpret_cast<const ushort4*>(hin)[(size_t)c * 64 + lane];
        a0 += v * bf2f(hv.x); a1 += v * bf2f(hv.y);
        a2 += v * bf2f(hv.z); a3 += v * bf2f(hv.w);
      }
    }
  }
  ushort4 o;
  o.x = f2bf(a0); o.y = f2bf(a1); o.z = f2bf(a2); o.w = f2bf(a3);
  reinterpret_cast<ushort4*>(hout)[(size_t)node * 64 + lane] = o;
}

// ---------- W[k][n] fp32 -> WT[n][k] bf16 ----------
__global__ __launch_bounds__(256) void wconv_kernel(
    const float* __restrict__ W, unsigned short* __restrict__ WT) {
  int k = blockIdx.x;
  int n = threadIdx.x;
  WT[(size_t)n * N_D + k] = f2bf(W[(size_t)k * N_D + n]);
}

// ---------- GEMM: H[M,256](bf16) @ W(256,256 via WT bf16) ----------
// Block: 256 thr = 4 waves; block rows [bx*64,+64); wave w covers cols [w*64,+64).
template <bool RELU, bool OUT_BF16>
__global__ __launch_bounds__(256) void gemm_csr(
    const unsigned short* __restrict__ H, const unsigned short* __restrict__ WT,
    void* __restrict__ C, int M) {
  const int wave = threadIdx.x >> 6;
  const int lane = threadIdx.x & 63;
  const int m = lane & 15;
  const int p = lane >> 4;
  const int row0 = blockIdx.x * 64;
  const int col0 = wave * 64;

  f32x4 acc[4][4];
#pragma unroll
  for (int i = 0; i < 4; ++i)
#pragma unroll
    for (int j = 0; j < 4; ++j) acc[i][j] = (f32x4){0.f, 0.f, 0.f, 0.f};

  for (int k0 = 0; k0 < N_D; k0 += 32) {
    bf16x8 a[4], b[4];
#pragma unroll
    for (int rt = 0; rt < 4; ++rt) {
      const int r = row0 + rt * 16 + m;
      if (r < M) {
        a[rt] = *reinterpret_cast<const bf16x8*>(H + (size_t)r * N_D + k0 + p * 8);
      } else {
        a[rt] = (bf16x8){0, 0, 0, 0, 0, 0, 0, 0};
      }
    }
#pragma unroll
    for (int nt = 0; nt < 4; ++nt) {
      b[nt] = *reinterpret_cast<const bf16x8*>(
          WT + (size_t)(col0 + nt * 16 + m) * N_D + k0 + p * 8);
    }
#pragma unroll
    for (int rt = 0; rt < 4; ++rt)
#pragma unroll
      for (int nt = 0; nt < 4; ++nt)
        acc[rt][nt] = __builtin_amdgcn_mfma_f32_16x16x32_bf16(a[rt], b[nt], acc[rt][nt], 0, 0, 0);
  }

  // C/D layout: col = lane&15 (=m), row = p*4 + rr within each 16x16 tile
#pragma unroll
  for (int rt = 0; rt < 4; ++rt) {
#pragma unroll
    for (int nt = 0; nt < 4; ++nt) {
      const int col = col0 + nt * 16 + m;
#pragma unroll
      for (int rr = 0; rr < 4; ++rr) {
        const int r = row0 + rt * 16 + p * 4 + rr;
        if (r < M) {
          float v = acc[rt][nt][rr];
          if (RELU) v = fmaxf(v, 0.f);
          if (OUT_BF16)
            ((unsigned short*)C)[(size_t)r * N_D + col] = f2bf(v);
          else
            ((float*)C)[(size_t)r * N_D + col] = v;
        }
      }
    }
  }
}

extern "C" void kernel_launch(void* const* d_in, const int* in_sizes, int n_in,
                              void* d_out, int out_size, void* d_ws, size_t ws_size,
                              hipStream_t stream) {
  const float* x    = (const float*)d_in[0];
  const float* vals = (const float*)d_in[1];
  const float* W0   = (const float*)d_in[2];
  const float* W1   = (const float*)d_in[3];
  const int*   rows = (const int*)d_in[4];
  const int*   cols = (const int*)d_in[5];

  const int n_edges = in_sizes[1];
  const int M = in_sizes[0] / N_D;   // 100000

  char* ws = (char*)d_ws;
  unsigned short* hA    = (unsigned short*)(ws);                    // 51.2 MB bf16
  int2*           colval = (int2*)(ws + 51200000);                  // 25.6 MB
  int*            row_ptr = (int*)(ws + 76800000);                  // 400 KB
  int*            cursor  = (int*)(ws + 77200128);                  // 400 KB
  int*            cnt     = (int*)(ws + 77600256);                  // 400 KB
  unsigned short* wt      = (unsigned short*)(ws + 78000384);       // 128 KB
  unsigned short* hB    = (unsigned short*)d_out;                   // bf16 view of d_out

  const int eblocks = (n_edges + 255) / 256;
  const int sblocks = (M + 3) / 4;          // 4 nodes (waves) per block
  const int gblocks = (M + 63) / 64;

  // --- CSR build (once; reused by all 4 SpMMs) ---
  hipMemsetAsync(cnt, 0, (size_t)M * sizeof(int), stream);
  hist_kernel<<<eblocks, 256, 0, stream>>>(rows, cnt, n_edges);
  scan_kernel<<<1, 1024, 0, stream>>>(cnt, row_ptr, M);
  hipMemcpyAsync(cursor, row_ptr, (size_t)M * sizeof(int),
                 hipMemcpyDeviceToDevice, stream);
  scatter_kernel<<<eblocks, 256, 0, stream>>>(rows, cols, vals, cursor, colval, n_edges);

  // --- layer 0 ---
  spmm_csr<true ><<<sblocks, 256, 0, stream>>>(x,  row_ptr, colval, hA, M);  // hA = 0.5*A x
  spmm_csr<false><<<sblocks, 256, 0, stream>>>(hA, row_ptr, colval, hB, M);  // hB = 0.5*A hA
  wconv_kernel<<<N_D, N_D, 0, stream>>>(W0, wt);
  gemm_csr<true, true><<<gblocks, 256, 0, stream>>>(hB, wt, hA, M);          // hA = relu(hB@W0)

  // --- layer 1 ---
  spmm_csr<false><<<sblocks, 256, 0, stream>>>(hA, row_ptr, colval, hB, M);
  spmm_csr<false><<<sblocks, 256, 0, stream>>>(hB, row_ptr, colval, hA, M);
  wconv_kernel<<<N_D, N_D, 0, stream>>>(W1, wt);
  gemm_csr<false, false><<<gblocks, 256, 0, stream>>>(hA, wt, d_out, M);     // out = hA@W1 (fp32)
}

// Round 3
// 1444.255 us; speedup vs baseline: 31.5977x; 1.2071x over previous
//
#include <hip/hip_runtime.h>
#include <hip/hip_bf16.h>

#define N_D 256

typedef __attribute__((ext_vector_type(8))) short bf16x8;
typedef __attribute__((ext_vector_type(4))) float f32x4;

// f32 -> bf16 round-to-nearest-even (finite inputs)
__device__ __forceinline__ unsigned short f2bf(float f) {
  union { float f; unsigned u; } c; c.f = f;
  unsigned u = c.u;
  return (unsigned short)((u + 0x7fffu + ((u >> 16) & 1u)) >> 16);
}
__device__ __forceinline__ float bf2f(unsigned short u) {
  union { unsigned u; float f; } c; c.u = ((unsigned)u) << 16;
  return c.f;
}

// ---------- fp32 -> bf16 bulk convert (for x) ----------
__global__ __launch_bounds__(256) void conv_kernel(
    const float* __restrict__ in, unsigned short* __restrict__ out, int n4) {
  int i = blockIdx.x * 256 + threadIdx.x;
  if (i < n4) {
    float4 v = reinterpret_cast<const float4*>(in)[i];
    ushort4 o;
    o.x = f2bf(v.x); o.y = f2bf(v.y); o.z = f2bf(v.z); o.w = f2bf(v.w);
    reinterpret_cast<ushort4*>(out)[i] = o;
  }
}

// ---------- CSR build ----------
__global__ __launch_bounds__(256) void hist_kernel(
    const int* __restrict__ rows, int* __restrict__ cnt, int n_edges) {
  int e = blockIdx.x * 256 + threadIdx.x;
  if (e < n_edges) atomicAdd(&cnt[rows[e]], 1);
}

// exclusive scan of cnt[0..n) -> row_ptr[0..n], single block of 1024
__global__ __launch_bounds__(1024) void scan_kernel(
    const int* __restrict__ cnt, int* __restrict__ row_ptr, int n) {
  __shared__ int sh[1024];
  __shared__ int carry_sh;
  const int tid = threadIdx.x;
  if (tid == 0) carry_sh = 0;
  __syncthreads();
  for (int base = 0; base < n; base += 1024) {
    int i = base + tid;
    int v = (i < n) ? cnt[i] : 0;
    int sum = v;
    sh[tid] = sum;
    __syncthreads();
#pragma unroll
    for (int off = 1; off < 1024; off <<= 1) {
      int prev = (tid >= off) ? sh[tid - off] : 0;
      __syncthreads();
      sum += prev;
      sh[tid] = sum;
      __syncthreads();
    }
    int carry = carry_sh;
    if (i < n) row_ptr[i] = carry + sum - v;   // exclusive
    __syncthreads();                           // everyone read carry_sh
    if (tid == 1023) carry_sh = carry + sum;
    __syncthreads();
  }
  if (tid == 0) row_ptr[n] = carry_sh;
}

// colval[pos] = (col, 0.5*val) grouped by destination row
__global__ __launch_bounds__(256) void scatter_kernel(
    const int* __restrict__ rows, const int* __restrict__ cols,
    const float* __restrict__ vals, int* __restrict__ cursor,
    int2* __restrict__ colval, int n_edges) {
  int e = blockIdx.x * 256 + threadIdx.x;
  if (e < n_edges) {
    int r = rows[e];
    int pos = atomicAdd(&cursor[r], 1);
    int2 cv;
    cv.x = cols[e];
    union { float f; int i; } c; c.f = vals[e] * 0.5f;
    cv.y = c.i;
    colval[pos] = cv;
  }
}

// ---------- SpMM: one wave per destination node, 8-deep pipelined gathers ----------
// hin is bf16 [n_nodes][256]; lane handles 8 bytes (ushort4).
__global__ __launch_bounds__(256) void spmm_csr(
    const unsigned short* __restrict__ hin, const int* __restrict__ row_ptr,
    const int2* __restrict__ colval, unsigned short* __restrict__ hout,
    int n_nodes) {
  const int node = (blockIdx.x * 256 + threadIdx.x) >> 6;  // wave-uniform
  const int lane = threadIdx.x & 63;
  if (node >= n_nodes) return;
  const int start = row_ptr[node];
  const int end   = row_ptr[node + 1];
  const ushort4* __restrict__ hv4 = reinterpret_cast<const ushort4*>(hin);

  float a0 = 0.f, a1 = 0.f, a2 = 0.f, a3 = 0.f;

  for (int base = start; base < end; base += 64) {
    const int cnt = min(64, end - base);
    // lanes beyond the row's edge list hold (c=0, v=0): harmless dummy gather
    int2 cv = make_int2(0, 0);
    if (base + lane < end) cv = colval[base + lane];
    for (int t = 0; t < cnt; t += 8) {
      ushort4 hv[8];
      float v[8];
#pragma unroll
      for (int j = 0; j < 8; ++j) {
        int c = __builtin_amdgcn_readlane(cv.x, t + j);
        union { int i; float f; } u;
        u.i = __builtin_amdgcn_readlane(cv.y, t + j);
        v[j] = u.f;
        hv[j] = hv4[(size_t)c * 64 + lane];   // 8 independent loads in flight
      }
#pragma unroll
      for (int j = 0; j < 8; ++j) {
        a0 += v[j] * bf2f(hv[j].x);
        a1 += v[j] * bf2f(hv[j].y);
        a2 += v[j] * bf2f(hv[j].z);
        a3 += v[j] * bf2f(hv[j].w);
      }
    }
  }
  ushort4 o;
  o.x = f2bf(a0); o.y = f2bf(a1); o.z = f2bf(a2); o.w = f2bf(a3);
  reinterpret_cast<ushort4*>(hout)[(size_t)node * 64 + lane] = o;
}

// ---------- W[k][n] fp32 -> WT[n][k] bf16 ----------
__global__ __launch_bounds__(256) void wconv_kernel(
    const float* __restrict__ W, unsigned short* __restrict__ WT) {
  int k = blockIdx.x;
  int n = threadIdx.x;
  WT[(size_t)n * N_D + k] = f2bf(W[(size_t)k * N_D + n]);
}

// ---------- GEMM: H[M,256](bf16) @ W(256,256 via WT bf16) ----------
// Block: 256 thr = 4 waves; block rows [bx*64,+64); wave w covers cols [w*64,+64).
template <bool RELU, bool OUT_BF16>
__global__ __launch_bounds__(256) void gemm_csr(
    const unsigned short* __restrict__ H, const unsigned short* __restrict__ WT,
    void* __restrict__ C, int M) {
  const int wave = threadIdx.x >> 6;
  const int lane = threadIdx.x & 63;
  const int m = lane & 15;
  const int p = lane >> 4;
  const int row0 = blockIdx.x * 64;
  const int col0 = wave * 64;

  f32x4 acc[4][4];
#pragma unroll
  for (int i = 0; i < 4; ++i)
#pragma unroll
    for (int j = 0; j < 4; ++j) acc[i][j] = (f32x4){0.f, 0.f, 0.f, 0.f};

  for (int k0 = 0; k0 < N_D; k0 += 32) {
    bf16x8 a[4], b[4];
#pragma unroll
    for (int rt = 0; rt < 4; ++rt) {
      const int r = row0 + rt * 16 + m;
      if (r < M) {
        a[rt] = *reinterpret_cast<const bf16x8*>(H + (size_t)r * N_D + k0 + p * 8);
      } else {
        a[rt] = (bf16x8){0, 0, 0, 0, 0, 0, 0, 0};
      }
    }
#pragma unroll
    for (int nt = 0; nt < 4; ++nt) {
      b[nt] = *reinterpret_cast<const bf16x8*>(
          WT + (size_t)(col0 + nt * 16 + m) * N_D + k0 + p * 8);
    }
#pragma unroll
    for (int rt = 0; rt < 4; ++rt)
#pragma unroll
      for (int nt = 0; nt < 4; ++nt)
        acc[rt][nt] = __builtin_amdgcn_mfma_f32_16x16x32_bf16(a[rt], b[nt], acc[rt][nt], 0, 0, 0);
  }

  // C/D layout: col = lane&15 (=m), row = p*4 + rr within each 16x16 tile
#pragma unroll
  for (int rt = 0; rt < 4; ++rt) {
#pragma unroll
    for (int nt = 0; nt < 4; ++nt) {
      const int col = col0 + nt * 16 + m;
#pragma unroll
      for (int rr = 0; rr < 4; ++rr) {
        const int r = row0 + rt * 16 + p * 4 + rr;
        if (r < M) {
          float v = acc[rt][nt][rr];
          if (RELU) v = fmaxf(v, 0.f);
          if (OUT_BF16)
            ((unsigned short*)C)[(size_t)r * N_D + col] = f2bf(v);
          else
            ((float*)C)[(size_t)r * N_D + col] = v;
        }
      }
    }
  }
}

extern "C" void kernel_launch(void* const* d_in, const int* in_sizes, int n_in,
                              void* d_out, int out_size, void* d_ws, size_t ws_size,
                              hipStream_t stream) {
  const float* x    = (const float*)d_in[0];
  const float* vals = (const float*)d_in[1];
  const float* W0   = (const float*)d_in[2];
  const float* W1   = (const float*)d_in[3];
  const int*   rows = (const int*)d_in[4];
  const int*   cols = (const int*)d_in[5];

  const int n_edges = in_sizes[1];
  const int M = in_sizes[0] / N_D;   // 100000
  const size_t n_feat = (size_t)M * N_D;  // 25.6M elements

  char* ws = (char*)d_ws;
  unsigned short* hA      = (unsigned short*)(ws);                  // 51.2 MB bf16
  int2*           colval  = (int2*)(ws + 51200000);                 // 25.6 MB
  int*            row_ptr = (int*)(ws + 76800000);                  // 400 KB
  int*            cursor  = (int*)(ws + 77200128);                  // 400 KB
  int*            cnt     = (int*)(ws + 77600256);                  // 400 KB
  unsigned short* wt      = (unsigned short*)(ws + 78000384);       // 128 KB
  // d_out (102.4 MB fp32) hosts two bf16 buffers until the final GEMM:
  unsigned short* hB = (unsigned short*)d_out;                      // lower 51.2 MB
  unsigned short* xb = (unsigned short*)d_out + n_feat;             // upper 51.2 MB

  const int eblocks = (n_edges + 255) / 256;
  const int sblocks = (M + 3) / 4;          // 4 nodes (waves) per block
  const int gblocks = (M + 63) / 64;
  const int cblocks = (int)(n_feat / 4 + 255) / 256;

  // --- CSR build (once; reused by all 4 SpMMs) ---
  hipMemsetAsync(cnt, 0, (size_t)M * sizeof(int), stream);
  hist_kernel<<<eblocks, 256, 0, stream>>>(rows, cnt, n_edges);
  scan_kernel<<<1, 1024, 0, stream>>>(cnt, row_ptr, M);
  hipMemcpyAsync(cursor, row_ptr, (size_t)M * sizeof(int),
                 hipMemcpyDeviceToDevice, stream);
  scatter_kernel<<<eblocks, 256, 0, stream>>>(rows, cols, vals, cursor, colval, n_edges);
  conv_kernel<<<cblocks, 256, 0, stream>>>(x, xb, (int)(n_feat / 4));

  // --- layer 0 ---
  spmm_csr<<<sblocks, 256, 0, stream>>>(xb, row_ptr, colval, hA, M);  // hA = 0.5*A x
  spmm_csr<<<sblocks, 256, 0, stream>>>(hA, row_ptr, colval, hB, M);  // hB = 0.5*A hA
  wconv_kernel<<<N_D, N_D, 0, stream>>>(W0, wt);
  gemm_csr<true, true><<<gblocks, 256, 0, stream>>>(hB, wt, hA, M);   // hA = relu(hB@W0)

  // --- layer 1 ---
  spmm_csr<<<sblocks, 256, 0, stream>>>(hA, row_ptr, colval, hB, M);
  spmm_csr<<<sblocks, 256, 0, stream>>>(hB, row_ptr, colval, hA, M);
  wconv_kernel<<<N_D, N_D, 0, stream>>>(W1, wt);
  gemm_csr<false, false><<<gblocks, 256, 0, stream>>>(hA, wt, d_out, M);  // out fp32
}

// Round 4
// 1383.455 us; speedup vs baseline: 32.9864x; 1.0439x over previous
//
#include <hip/hip_runtime.h>
#include <hip/hip_bf16.h>
#include <hip/hip_fp16.h>

#define N_D 256

typedef __attribute__((ext_vector_type(8))) short bf16x8;
typedef __attribute__((ext_vector_type(4))) float f32x4;

// f32 -> bf16 round-to-nearest-even (finite inputs)
__device__ __forceinline__ unsigned short f2bf(float f) {
  union { float f; unsigned u; } c; c.f = f;
  unsigned u = c.u;
  return (unsigned short)((u + 0x7fffu + ((u >> 16) & 1u)) >> 16);
}
__device__ __forceinline__ float asf(unsigned u) {
  union { unsigned u; float f; } c; c.u = u;
  return c.f;
}

// ---------- fp32 -> bf16 bulk convert (for x) ----------
__global__ __launch_bounds__(256) void conv_kernel(
    const float* __restrict__ in, unsigned short* __restrict__ out, int n4) {
  int i = blockIdx.x * 256 + threadIdx.x;
  if (i < n4) {
    float4 v = reinterpret_cast<const float4*>(in)[i];
    ushort4 o;
    o.x = f2bf(v.x); o.y = f2bf(v.y); o.z = f2bf(v.z); o.w = f2bf(v.w);
    reinterpret_cast<ushort4*>(out)[i] = o;
  }
}

// ---------- CSR build ----------
__global__ __launch_bounds__(256) void hist_kernel(
    const int* __restrict__ rows, int* __restrict__ cnt, int n_edges) {
  int e = blockIdx.x * 256 + threadIdx.x;
  if (e < n_edges) atomicAdd(&cnt[rows[e]], 1);
}

// exclusive scan of cnt[0..n) -> row_ptr[0..n] and cursor[0..n); 1 block x 1024.
// Per 4096-chunk: thread-local sum of 4, wave shfl-scan, cross-wave LDS scan.
__global__ __launch_bounds__(1024) void scan_kernel(
    const int* __restrict__ cnt, int* __restrict__ row_ptr,
    int* __restrict__ cursor, int n) {
  __shared__ int wsum[16];
  __shared__ int carry_sh;
  const int tid = threadIdx.x;
  const int lane = tid & 63;
  const int wid = tid >> 6;
  if (tid == 0) carry_sh = 0;
  __syncthreads();
  for (int base = 0; base < n; base += 4096) {
    const int i0 = base + tid * 4;
    int4 v = make_int4(0, 0, 0, 0);
    if (i0 + 3 < n) v = *reinterpret_cast<const int4*>(cnt + i0);
    else {
      if (i0     < n) v.x = cnt[i0];
      if (i0 + 1 < n) v.y = cnt[i0 + 1];
      if (i0 + 2 < n) v.z = cnt[i0 + 2];
    }
    const int s1 = v.x, s2 = s1 + v.y, s3 = s2 + v.z, s4 = s3 + v.w;
    int ws = s4;                       // wave-inclusive scan of per-thread sums
#pragma unroll
    for (int off = 1; off < 64; off <<= 1) {
      int o = __shfl_up(ws, off, 64);
      if (lane >= off) ws += o;
    }
    if (lane == 63) wsum[wid] = ws;
    __syncthreads();
    if (wid == 0) {
      int t = (lane < 16) ? wsum[lane] : 0;
#pragma unroll
      for (int off = 1; off < 16; off <<= 1) {
        int o = __shfl_up(t, off, 64);
        if (lane >= off) t += o;
      }
      if (lane < 16) wsum[lane] = t;   // inclusive wave-prefix
    }
    __syncthreads();
    const int carry = carry_sh;
    const int tbase = carry + (wid ? wsum[wid - 1] : 0) + ws - s4;  // exclusive
    if (i0     < n) { row_ptr[i0]     = tbase;      cursor[i0]     = tbase; }
    if (i0 + 1 < n) { row_ptr[i0 + 1] = tbase + s1; cursor[i0 + 1] = tbase + s1; }
    if (i0 + 2 < n) { row_ptr[i0 + 2] = tbase + s2; cursor[i0 + 2] = tbase + s2; }
    if (i0 + 3 < n) { row_ptr[i0 + 3] = tbase + s3; cursor[i0 + 3] = tbase + s3; }
    __syncthreads();                   // protect wsum/carry_sh
    if (tid == 0) carry_sh = carry + wsum[15];
    __syncthreads();
  }
  if (tid == 0) row_ptr[n] = carry_sh;
}

// colpack[pos] = (col<<15) | (f16(0.5*val)>>1), grouped by destination row.
// 8 block-groups (bid%8 -> XCD); group g only scatters rows in its range so
// same-segment writes merge in one XCD's L2 (kills the 8x write amplification).
__global__ __launch_bounds__(256) void scatter_kernel(
    const int* __restrict__ rows, const int* __restrict__ cols,
    const float* __restrict__ vals, int* __restrict__ cursor,
    unsigned* __restrict__ colpack, int n_edges, int rows_per_group) {
  const int g  = blockIdx.x & 7;
  const int nb = gridDim.x >> 3;
  const int bk = blockIdx.x >> 3;
  const int r0 = g * rows_per_group;
  const int r1 = (g == 7) ? 0x7fffffff : r0 + rows_per_group;
  for (int e = bk * 256 + threadIdx.x; e < n_edges; e += nb * 256) {
    const int r = rows[e];
    if (r >= r0 && r < r1) {
      const int pos = atomicAdd(&cursor[r], 1);
      const unsigned short hb = __half_as_ushort(__float2half_rn(vals[e] * 0.5f));
      colpack[pos] = ((unsigned)cols[e] << 15) | ((unsigned)hb >> 1);
    }
  }
}

// ---------- SpMM: one wave per destination node ----------
// Half-wave layout: sub = lane&31 covers 16B (8 bf16 cols [sub*8,+8));
// half = lane>>5 processes even(0)/odd(1) edge slots. 8 loads = 16 edges in flight.
__global__ __launch_bounds__(256) void spmm_csr(
    const unsigned short* __restrict__ hin, const int* __restrict__ row_ptr,
    const unsigned* __restrict__ colpack, unsigned short* __restrict__ hout,
    int n_nodes) {
  const int node = (blockIdx.x * 256 + threadIdx.x) >> 6;  // wave-uniform
  const int lane = threadIdx.x & 63;
  const int sub  = lane & 31;
  const int half = lane >> 5;
  if (node >= n_nodes) return;
  const int start = row_ptr[node];
  const int end   = row_ptr[node + 1];
  const uint4* __restrict__ hin4 = reinterpret_cast<const uint4*>(hin);

  float acc[8];
#pragma unroll
  for (int i = 0; i < 8; ++i) acc[i] = 0.f;

  for (int base = start; base < end; base += 64) {
    const int cnt = min(64, end - base);
    // zero-padded window: u=0 decodes to (col=0, val=0) -> harmless dummy
    unsigned u = 0;
    if (base + lane < end) u = colpack[base + lane];
    for (int t = 0; t < cnt; t += 16) {
      uint4 hv[8];
      float v[8];
#pragma unroll
      for (int j = 0; j < 8; ++j) {
        const unsigned ue = (unsigned)__shfl((int)u, t + 2 * j + half, 64);
        const int c = (int)(ue >> 15);
        v[j] = __half2float(__ushort_as_half((unsigned short)((ue & 0x7fffu) << 1)));
        hv[j] = hin4[(size_t)c * 32 + sub];   // 8 independent 16B gathers
      }
#pragma unroll
      for (int j = 0; j < 8; ++j) {
        acc[0] += v[j] * asf(hv[j].x << 16);
        acc[1] += v[j] * asf(hv[j].x & 0xffff0000u);
        acc[2] += v[j] * asf(hv[j].y << 16);
        acc[3] += v[j] * asf(hv[j].y & 0xffff0000u);
        acc[4] += v[j] * asf(hv[j].z << 16);
        acc[5] += v[j] * asf(hv[j].z & 0xffff0000u);
        acc[6] += v[j] * asf(hv[j].w << 16);
        acc[7] += v[j] * asf(hv[j].w & 0xffff0000u);
      }
    }
  }
  // combine even/odd halves: partner lane is lane^32
#pragma unroll
  for (int i = 0; i < 8; ++i) acc[i] += __shfl_xor(acc[i], 32, 64);
  if (half == 0) {
    uint4 o;
    o.x = (unsigned)f2bf(acc[0]) | ((unsigned)f2bf(acc[1]) << 16);
    o.y = (unsigned)f2bf(acc[2]) | ((unsigned)f2bf(acc[3]) << 16);
    o.z = (unsigned)f2bf(acc[4]) | ((unsigned)f2bf(acc[5]) << 16);
    o.w = (unsigned)f2bf(acc[6]) | ((unsigned)f2bf(acc[7]) << 16);
    reinterpret_cast<uint4*>(hout)[(size_t)node * 32 + sub] = o;
  }
}

// ---------- W[k][n] fp32 -> WT[n][k] bf16 ----------
__global__ __launch_bounds__(256) void wconv_kernel(
    const float* __restrict__ W, unsigned short* __restrict__ WT) {
  int k = blockIdx.x;
  int n = threadIdx.x;
  WT[(size_t)n * N_D + k] = f2bf(W[(size_t)k * N_D + n]);
}

// ---------- GEMM: H[M,256](bf16) @ W(256,256 via WT bf16) ----------
template <bool RELU, bool OUT_BF16>
__global__ __launch_bounds__(256) void gemm_csr(
    const unsigned short* __restrict__ H, const unsigned short* __restrict__ WT,
    void* __restrict__ C, int M) {
  const int wave = threadIdx.x >> 6;
  const int lane = threadIdx.x & 63;
  const int m = lane & 15;
  const int p = lane >> 4;
  const int row0 = blockIdx.x * 64;
  const int col0 = wave * 64;

  f32x4 acc[4][4];
#pragma unroll
  for (int i = 0; i < 4; ++i)
#pragma unroll
    for (int j = 0; j < 4; ++j) acc[i][j] = (f32x4){0.f, 0.f, 0.f, 0.f};

  for (int k0 = 0; k0 < N_D; k0 += 32) {
    bf16x8 a[4], b[4];
#pragma unroll
    for (int rt = 0; rt < 4; ++rt) {
      const int r = row0 + rt * 16 + m;
      if (r < M) {
        a[rt] = *reinterpret_cast<const bf16x8*>(H + (size_t)r * N_D + k0 + p * 8);
      } else {
        a[rt] = (bf16x8){0, 0, 0, 0, 0, 0, 0, 0};
      }
    }
#pragma unroll
    for (int nt = 0; nt < 4; ++nt) {
      b[nt] = *reinterpret_cast<const bf16x8*>(
          WT + (size_t)(col0 + nt * 16 + m) * N_D + k0 + p * 8);
    }
#pragma unroll
    for (int rt = 0; rt < 4; ++rt)
#pragma unroll
      for (int nt = 0; nt < 4; ++nt)
        acc[rt][nt] = __builtin_amdgcn_mfma_f32_16x16x32_bf16(a[rt], b[nt], acc[rt][nt], 0, 0, 0);
  }

#pragma unroll
  for (int rt = 0; rt < 4; ++rt) {
#pragma unroll
    for (int nt = 0; nt < 4; ++nt) {
      const int col = col0 + nt * 16 + m;
#pragma unroll
      for (int rr = 0; rr < 4; ++rr) {
        const int r = row0 + rt * 16 + p * 4 + rr;
        if (r < M) {
          float v = acc[rt][nt][rr];
          if (RELU) v = fmaxf(v, 0.f);
          if (OUT_BF16)
            ((unsigned short*)C)[(size_t)r * N_D + col] = f2bf(v);
          else
            ((float*)C)[(size_t)r * N_D + col] = v;
        }
      }
    }
  }
}

extern "C" void kernel_launch(void* const* d_in, const int* in_sizes, int n_in,
                              void* d_out, int out_size, void* d_ws, size_t ws_size,
                              hipStream_t stream) {
  const float* x    = (const float*)d_in[0];
  const float* vals = (const float*)d_in[1];
  const float* W0   = (const float*)d_in[2];
  const float* W1   = (const float*)d_in[3];
  const int*   rows = (const int*)d_in[4];
  const int*   cols = (const int*)d_in[5];

  const int n_edges = in_sizes[1];
  const int M = in_sizes[0] / N_D;        // 100000
  const size_t n_feat = (size_t)M * N_D;  // 25.6M elements

  char* ws = (char*)d_ws;
  unsigned short* hA      = (unsigned short*)(ws);                  // 51.2 MB bf16
  unsigned*       colpack = (unsigned*)(ws + 51200000);             // 12.8 MB
  int*            row_ptr = (int*)(ws + 76800000);                  // 400 KB
  int*            cursor  = (int*)(ws + 77200128);                  // 400 KB
  int*            cnt     = (int*)(ws + 77600256);                  // 400 KB
  unsigned short* wt      = (unsigned short*)(ws + 78000384);       // 128 KB
  // d_out (102.4 MB fp32) hosts two bf16 buffers until the final GEMM:
  unsigned short* hB = (unsigned short*)d_out;                      // lower 51.2 MB
  unsigned short* xb = (unsigned short*)d_out + n_feat;             // upper 51.2 MB

  const int eblocks = (n_edges + 255) / 256;
  const int sblocks = (M + 3) / 4;          // 4 nodes (waves) per block
  const int gblocks = (M + 63) / 64;
  const int cblocks = (int)(n_feat / 4 + 255) / 256;
  const int rpg = (M + 7) / 8;              // rows per scatter group

  // --- CSR build (once; reused by all 4 SpMMs) ---
  hipMemsetAsync(cnt, 0, (size_t)M * sizeof(int), stream);
  hist_kernel<<<eblocks, 256, 0, stream>>>(rows, cnt, n_edges);
  scan_kernel<<<1, 1024, 0, stream>>>(cnt, row_ptr, cursor, M);
  scatter_kernel<<<8 * 104, 256, 0, stream>>>(rows, cols, vals, cursor, colpack,
                                              n_edges, rpg);
  conv_kernel<<<cblocks, 256, 0, stream>>>(x, xb, (int)(n_feat / 4));

  // --- layer 0 ---
  spmm_csr<<<sblocks, 256, 0, stream>>>(xb, row_ptr, colpack, hA, M);  // hA = 0.5*A x
  spmm_csr<<<sblocks, 256, 0, stream>>>(hA, row_ptr, colpack, hB, M);  // hB = 0.5*A hA
  wconv_kernel<<<N_D, N_D, 0, stream>>>(W0, wt);
  gemm_csr<true, true><<<gblocks, 256, 0, stream>>>(hB, wt, hA, M);    // hA = relu(hB@W0)

  // --- layer 1 ---
  spmm_csr<<<sblocks, 256, 0, stream>>>(hA, row_ptr, colpack, hB, M);
  spmm_csr<<<sblocks, 256, 0, stream>>>(hB, row_ptr, colpack, hA, M);
  wconv_kernel<<<N_D, N_D, 0, stream>>>(W1, wt);
  gemm_csr<false, false><<<gblocks, 256, 0, stream>>>(hA, wt, d_out, M);  // out fp32
}

// Round 5
// 1376.875 us; speedup vs baseline: 33.1440x; 1.0048x over previous
//
#include <hip/hip_runtime.h>
#include <hip/hip_bf16.h>
#include <hip/hip_fp16.h>

#define N_D 256
#define NBLK 832   // edge-pass grid; must match between count/partition kernels

typedef __attribute__((ext_vector_type(8))) short bf16x8;
typedef __attribute__((ext_vector_type(4))) float f32x4;

// f32 -> bf16 round-to-nearest-even (finite inputs)
__device__ __forceinline__ unsigned short f2bf(float f) {
  union { float f; unsigned u; } c; c.f = f;
  unsigned u = c.u;
  return (unsigned short)((u + 0x7fffu + ((u >> 16) & 1u)) >> 16);
}
__device__ __forceinline__ float asf(unsigned u) {
  union { unsigned u; float f; } c; c.u = u;
  return c.f;
}
__device__ __forceinline__ int grp_of(int r, unsigned gmagic) {
  int g = (int)(((unsigned long long)(unsigned)r * gmagic) >> 37);
  return min(g, 7);
}

// ---------- fp32 -> bf16 bulk convert (for x) ----------
__global__ __launch_bounds__(256) void conv_kernel(
    const float* __restrict__ in, unsigned short* __restrict__ out, int n4) {
  int i = blockIdx.x * 256 + threadIdx.x;
  if (i < n4) {
    float4 v = reinterpret_cast<const float4*>(in)[i];
    ushort4 o;
    o.x = f2bf(v.x); o.y = f2bf(v.y); o.z = f2bf(v.z); o.w = f2bf(v.w);
    reinterpret_cast<ushort4*>(out)[i] = o;
  }
}

// ---------- CSR build pass 1: row histogram + per-(group,block) counts ----------
__global__ __launch_bounds__(256) void count_kernel(
    const int* __restrict__ rows, int* __restrict__ cnt, int* __restrict__ cntT,
    int n_edges, unsigned gmagic) {
  __shared__ int lcnt[8];
  if (threadIdx.x < 8) lcnt[threadIdx.x] = 0;
  __syncthreads();
  for (int e = blockIdx.x * 256 + threadIdx.x; e < n_edges; e += NBLK * 256) {
    const int r = rows[e];
    atomicAdd(&cnt[r], 1);
    atomicAdd(&lcnt[grp_of(r, gmagic)], 1);
  }
  __syncthreads();
  if (threadIdx.x < 8) cntT[threadIdx.x * NBLK + blockIdx.x] = lcnt[threadIdx.x];
}

// exclusive scan of cnt[0..n) -> outA[0..n] and outB[0..n); 1 block x 1024.
__global__ __launch_bounds__(1024) void scan_kernel(
    const int* __restrict__ cnt, int* __restrict__ outA,
    int* __restrict__ outB, int n) {
  __shared__ int wsum[16];
  __shared__ int carry_sh;
  const int tid = threadIdx.x;
  const int lane = tid & 63;
  const int wid = tid >> 6;
  if (tid == 0) carry_sh = 0;
  __syncthreads();
  for (int base = 0; base < n; base += 4096) {
    const int i0 = base + tid * 4;
    int4 v = make_int4(0, 0, 0, 0);
    if (i0 + 3 < n) v = *reinterpret_cast<const int4*>(cnt + i0);
    else {
      if (i0     < n) v.x = cnt[i0];
      if (i0 + 1 < n) v.y = cnt[i0 + 1];
      if (i0 + 2 < n) v.z = cnt[i0 + 2];
    }
    const int s1 = v.x, s2 = s1 + v.y, s3 = s2 + v.z, s4 = s3 + v.w;
    int ws = s4;
#pragma unroll
    for (int off = 1; off < 64; off <<= 1) {
      int o = __shfl_up(ws, off, 64);
      if (lane >= off) ws += o;
    }
    if (lane == 63) wsum[wid] = ws;
    __syncthreads();
    if (wid == 0) {
      int t = (lane < 16) ? wsum[lane] : 0;
#pragma unroll
      for (int off = 1; off < 16; off <<= 1) {
        int o = __shfl_up(t, off, 64);
        if (lane >= off) t += o;
      }
      if (lane < 16) wsum[lane] = t;
    }
    __syncthreads();
    const int carry = carry_sh;
    const int tbase = carry + (wid ? wsum[wid - 1] : 0) + ws - s4;  // exclusive
    if (i0     < n) { outA[i0]     = tbase;      outB[i0]     = tbase; }
    if (i0 + 1 < n) { outA[i0 + 1] = tbase + s1; outB[i0 + 1] = tbase + s1; }
    if (i0 + 2 < n) { outA[i0 + 2] = tbase + s2; outB[i0 + 2] = tbase + s2; }
    if (i0 + 3 < n) { outA[i0 + 3] = tbase + s3; outB[i0 + 3] = tbase + s3; }
    __syncthreads();
    if (tid == 0) carry_sh = carry + wsum[15];
    __syncthreads();
  }
  if (tid == 0) outA[n] = carry_sh;
}

// ---------- pass 2: partition edges into 8 contiguous group segments ----------
__global__ __launch_bounds__(256) void partition_kernel(
    const int* __restrict__ rows, const int* __restrict__ cols,
    const float* __restrict__ vals, const int* __restrict__ pofsT,
    int2* __restrict__ part, int n_edges, unsigned gmagic) {
  __shared__ int lofs[8];
  if (threadIdx.x < 8) lofs[threadIdx.x] = pofsT[threadIdx.x * NBLK + blockIdx.x];
  __syncthreads();
  for (int e = blockIdx.x * 256 + threadIdx.x; e < n_edges; e += NBLK * 256) {
    const int r = rows[e];
    const int g = grp_of(r, gmagic);
    const int slot = atomicAdd(&lofs[g], 1);
    const unsigned short hb = __half_as_ushort(__float2half_rn(vals[e] * 0.5f));
    int2 rv;
    rv.x = r;
    rv.y = (int)(((unsigned)cols[e] << 15) | ((unsigned)hb >> 1));
    part[slot] = rv;
  }
}

// ---------- pass 3: scatter within XCD-local group (write-merge friendly) ----------
__global__ __launch_bounds__(256) void scatter2_kernel(
    const int2* __restrict__ part, const int* __restrict__ pofsT,
    int* __restrict__ cursor, unsigned* __restrict__ colpack) {
  const int g  = blockIdx.x & 7;
  const int bk = blockIdx.x >> 3;
  const int nb = gridDim.x >> 3;
  const int s0 = pofsT[g * NBLK];
  const int s1 = pofsT[(g + 1) * NBLK];   // g=7 -> pofsT[8*NBLK] = total
  for (int i = s0 + bk * 256 + threadIdx.x; i < s1; i += nb * 256) {
    const int2 rv = part[i];
    const int pos = atomicAdd(&cursor[rv.x], 1);
    colpack[pos] = (unsigned)rv.y;
  }
}

// ---------- SpMM: two nodes per wave (one per half-wave) ----------
// Half-wave: 32 lanes x 16B = one 512B row; 8 gathers in flight; 8-edge padding.
__global__ __launch_bounds__(256) void spmm_csr(
    const unsigned short* __restrict__ hin, const int* __restrict__ row_ptr,
    const unsigned* __restrict__ colpack, unsigned short* __restrict__ hout,
    int n_nodes) {
  const int lane = threadIdx.x & 63;
  const int half = lane >> 5;
  const int sub  = lane & 31;
  const int wgid = (blockIdx.x * 256 + threadIdx.x) >> 6;
  const int node = wgid * 2 + half;          // per half-wave
  const bool ok = node < n_nodes;
  int start = 0, end = 0;
  if (ok) { start = row_ptr[node]; end = row_ptr[node + 1]; }
  const uint4* __restrict__ hin4 = reinterpret_cast<const uint4*>(hin);

  float acc[8];
#pragma unroll
  for (int i = 0; i < 8; ++i) acc[i] = 0.f;

  for (int base = start; base < end; base += 32) {
    const int cnt = min(32, end - base);
    unsigned u = 0;                          // u=0 decodes to (col=0, val=0)
    if (base + sub < end) u = colpack[base + sub];
    for (int t = 0; t < cnt; t += 8) {
      uint4 hv[8];
      float v[8];
#pragma unroll
      for (int j = 0; j < 8; ++j) {
        const unsigned ue = (unsigned)__shfl((int)u, (half << 5) + t + j, 64);
        const int c = (int)(ue >> 15);
        v[j] = __half2float(__ushort_as_half((unsigned short)((ue & 0x7fffu) << 1)));
        hv[j] = hin4[(size_t)c * 32 + sub];  // 8 independent 16B gathers
      }
#pragma unroll
      for (int j = 0; j < 8; ++j) {
        acc[0] += v[j] * asf(hv[j].x << 16);
        acc[1] += v[j] * asf(hv[j].x & 0xffff0000u);
        acc[2] += v[j] * asf(hv[j].y << 16);
        acc[3] += v[j] * asf(hv[j].y & 0xffff0000u);
        acc[4] += v[j] * asf(hv[j].z << 16);
        acc[5] += v[j] * asf(hv[j].z & 0xffff0000u);
        acc[6] += v[j] * asf(hv[j].w << 16);
        acc[7] += v[j] * asf(hv[j].w & 0xffff0000u);
      }
    }
  }
  if (ok) {
    uint4 o;
    o.x = (unsigned)f2bf(acc[0]) | ((unsigned)f2bf(acc[1]) << 16);
    o.y = (unsigned)f2bf(acc[2]) | ((unsigned)f2bf(acc[3]) << 16);
    o.z = (unsigned)f2bf(acc[4]) | ((unsigned)f2bf(acc[5]) << 16);
    o.w = (unsigned)f2bf(acc[6]) | ((unsigned)f2bf(acc[7]) << 16);
    reinterpret_cast<uint4*>(hout)[(size_t)node * 32 + sub] = o;
  }
}

// ---------- W[k][n] fp32 -> WT[n][k] bf16 ----------
__global__ __launch_bounds__(256) void wconv_kernel(
    const float* __restrict__ W, unsigned short* __restrict__ WT) {
  int k = blockIdx.x;
  int n = threadIdx.x;
  WT[(size_t)n * N_D + k] = f2bf(W[(size_t)k * N_D + n]);
}

// ---------- GEMM: H[M,256](bf16) @ W(256,256 via WT bf16) ----------
template <bool RELU, bool OUT_BF16>
__global__ __launch_bounds__(256) void gemm_csr(
    const unsigned short* __restrict__ H, const unsigned short* __restrict__ WT,
    void* __restrict__ C, int M) {
  const int wave = threadIdx.x >> 6;
  const int lane = threadIdx.x & 63;
  const int m = lane & 15;
  const int p = lane >> 4;
  const int row0 = blockIdx.x * 64;
  const int col0 = wave * 64;

  f32x4 acc[4][4];
#pragma unroll
  for (int i = 0; i < 4; ++i)
#pragma unroll
    for (int j = 0; j < 4; ++j) acc[i][j] = (f32x4){0.f, 0.f, 0.f, 0.f};

  for (int k0 = 0; k0 < N_D; k0 += 32) {
    bf16x8 a[4], b[4];
#pragma unroll
    for (int rt = 0; rt < 4; ++rt) {
      const int r = row0 + rt * 16 + m;
      if (r < M) {
        a[rt] = *reinterpret_cast<const bf16x8*>(H + (size_t)r * N_D + k0 + p * 8);
      } else {
        a[rt] = (bf16x8){0, 0, 0, 0, 0, 0, 0, 0};
      }
    }
#pragma unroll
    for (int nt = 0; nt < 4; ++nt) {
      b[nt] = *reinterpret_cast<const bf16x8*>(
          WT + (size_t)(col0 + nt * 16 + m) * N_D + k0 + p * 8);
    }
#pragma unroll
    for (int rt = 0; rt < 4; ++rt)
#pragma unroll
      for (int nt = 0; nt < 4; ++nt)
        acc[rt][nt] = __builtin_amdgcn_mfma_f32_16x16x32_bf16(a[rt], b[nt], acc[rt][nt], 0, 0, 0);
  }

#pragma unroll
  for (int rt = 0; rt < 4; ++rt) {
#pragma unroll
    for (int nt = 0; nt < 4; ++nt) {
      const int col = col0 + nt * 16 + m;
#pragma unroll
      for (int rr = 0; rr < 4; ++rr) {
        const int r = row0 + rt * 16 + p * 4 + rr;
        if (r < M) {
          float v = acc[rt][nt][rr];
          if (RELU) v = fmaxf(v, 0.f);
          if (OUT_BF16)
            ((unsigned short*)C)[(size_t)r * N_D + col] = f2bf(v);
          else
            ((float*)C)[(size_t)r * N_D + col] = v;
        }
      }
    }
  }
}

extern "C" void kernel_launch(void* const* d_in, const int* in_sizes, int n_in,
                              void* d_out, int out_size, void* d_ws, size_t ws_size,
                              hipStream_t stream) {
  const float* x    = (const float*)d_in[0];
  const float* vals = (const float*)d_in[1];
  const float* W0   = (const float*)d_in[2];
  const float* W1   = (const float*)d_in[3];
  const int*   rows = (const int*)d_in[4];
  const int*   cols = (const int*)d_in[5];

  const int n_edges = in_sizes[1];
  const int M = in_sizes[0] / N_D;        // 100000
  const size_t n_feat = (size_t)M * N_D;  // 25.6M elements

  char* ws = (char*)d_ws;
  unsigned short* hA      = (unsigned short*)(ws);                  // 51.2 MB bf16
  unsigned*       colpack = (unsigned*)(ws + 51200000);             // 12.8 MB
  int*            row_ptr = (int*)(ws + 64000000);                  // 400 KB
  int*            cursor  = (int*)(ws + 64400128);                  // 400 KB
  int*            cnt     = (int*)(ws + 64800256);                  // 400 KB
  int*            cntT    = (int*)(ws + 65200384);                  // 26.6 KB
  int*            pofsT   = (int*)(ws + 65227264);                  // 26.6 KB
  int*            pscr    = (int*)(ws + 65254144);                  // 26.6 KB
  unsigned short* wt      = (unsigned short*)(ws + 65281024);       // 128 KB
  // d_out (102.4 MB fp32) hosts bf16/scratch buffers until the final GEMM:
  unsigned short* hB   = (unsigned short*)d_out;                    // lower 51.2 MB
  unsigned short* xb   = (unsigned short*)d_out + n_feat;           // upper 51.2 MB
  int2*           part = (int2*)((char*)d_out + 51200000);          // 25.6 MB (dead until conv)

  const int sblocks = (M + 7) / 8;          // 8 nodes (2 per wave x 4 waves) per block
  const int gblocks = (M + 63) / 64;
  const int cblocks = (int)(n_feat / 4 + 255) / 256;
  const int rpg = (M + 7) / 8;              // rows per XCD group
  const unsigned gmagic = (unsigned)(((1ULL << 37) + rpg - 1) / (unsigned long long)rpg);

  // --- CSR build (once; reused by all 4 SpMMs) ---
  hipMemsetAsync(cnt, 0, (size_t)M * sizeof(int), stream);
  count_kernel<<<NBLK, 256, 0, stream>>>(rows, cnt, cntT, n_edges, gmagic);
  scan_kernel<<<1, 1024, 0, stream>>>(cnt, row_ptr, cursor, M);
  scan_kernel<<<1, 1024, 0, stream>>>(cntT, pofsT, pscr, 8 * NBLK);
  partition_kernel<<<NBLK, 256, 0, stream>>>(rows, cols, vals, pofsT, part,
                                             n_edges, gmagic);
  scatter2_kernel<<<NBLK, 256, 0, stream>>>(part, pofsT, cursor, colpack);
  conv_kernel<<<cblocks, 256, 0, stream>>>(x, xb, (int)(n_feat / 4));  // after part is dead

  // --- layer 0 ---
  spmm_csr<<<sblocks, 256, 0, stream>>>(xb, row_ptr, colpack, hA, M);  // hA = 0.5*A x
  spmm_csr<<<sblocks, 256, 0, stream>>>(hA, row_ptr, colpack, hB, M);  // hB = 0.5*A hA
  wconv_kernel<<<N_D, N_D, 0, stream>>>(W0, wt);
  gemm_csr<true, true><<<gblocks, 256, 0, stream>>>(hB, wt, hA, M);    // hA = relu(hB@W0)

  // --- layer 1 ---
  spmm_csr<<<sblocks, 256, 0, stream>>>(hA, row_ptr, colpack, hB, M);
  spmm_csr<<<sblocks, 256, 0, stream>>>(hB, row_ptr, colpack, hA, M);
  wconv_kernel<<<N_D, N_D, 0, stream>>>(W1, wt);
  gemm_csr<false, false><<<gblocks, 256, 0, stream>>>(hA, wt, d_out, M);  // out fp32
}

// Round 6
// 1224.070 us; speedup vs baseline: 37.2815x; 1.1248x over previous
//
#include <hip/hip_runtime.h>
#include <hip/hip_bf16.h>
#include <hip/hip_fp16.h>

#define N_D 256
#define NBLK 832   // edge-pass grid; must match between count/partition kernels

typedef __attribute__((ext_vector_type(8))) short bf16x8;
typedef __attribute__((ext_vector_type(4))) float f32x4;

// f32 -> bf16 round-to-nearest-even (finite inputs)
__device__ __forceinline__ unsigned short f2bf(float f) {
  union { float f; unsigned u; } c; c.f = f;
  unsigned u = c.u;
  return (unsigned short)((u + 0x7fffu + ((u >> 16) & 1u)) >> 16);
}
__device__ __forceinline__ float asf(unsigned u) {
  union { unsigned u; float f; } c; c.u = u;
  return c.f;
}
__device__ __forceinline__ int grp_of(int r, unsigned gmagic) {
  int g = (int)(((unsigned long long)(unsigned)r * gmagic) >> 37);
  return min(g, 7);
}

// ---------- fp32 -> bf16 bulk convert (for x) ----------
__global__ __launch_bounds__(256) void conv_kernel(
    const float* __restrict__ in, unsigned short* __restrict__ out, int n4) {
  int i = blockIdx.x * 256 + threadIdx.x;
  if (i < n4) {
    float4 v = reinterpret_cast<const float4*>(in)[i];
    ushort4 o;
    o.x = f2bf(v.x); o.y = f2bf(v.y); o.z = f2bf(v.z); o.w = f2bf(v.w);
    reinterpret_cast<ushort4*>(out)[i] = o;
  }
}

// ---------- CSR build pass 1: row histogram + per-(group,block) counts ----------
__global__ __launch_bounds__(256) void count_kernel(
    const int* __restrict__ rows, int* __restrict__ cnt, int* __restrict__ cntT,
    int n_edges, unsigned gmagic) {
  __shared__ int lcnt[8];
  if (threadIdx.x < 8) lcnt[threadIdx.x] = 0;
  __syncthreads();
  for (int e = blockIdx.x * 256 + threadIdx.x; e < n_edges; e += NBLK * 256) {
    const int r = rows[e];
    atomicAdd(&cnt[r], 1);
    atomicAdd(&lcnt[grp_of(r, gmagic)], 1);
  }
  __syncthreads();
  if (threadIdx.x < 8) cntT[threadIdx.x * NBLK + blockIdx.x] = lcnt[threadIdx.x];
}

// exclusive scan of cnt[0..n) -> outA[0..n] and outB[0..n); 1 block x 1024.
__global__ __launch_bounds__(1024) void scan_kernel(
    const int* __restrict__ cnt, int* __restrict__ outA,
    int* __restrict__ outB, int n) {
  __shared__ int wsum[16];
  __shared__ int carry_sh;
  const int tid = threadIdx.x;
  const int lane = tid & 63;
  const int wid = tid >> 6;
  if (tid == 0) carry_sh = 0;
  __syncthreads();
  for (int base = 0; base < n; base += 4096) {
    const int i0 = base + tid * 4;
    int4 v = make_int4(0, 0, 0, 0);
    if (i0 + 3 < n) v = *reinterpret_cast<const int4*>(cnt + i0);
    else {
      if (i0     < n) v.x = cnt[i0];
      if (i0 + 1 < n) v.y = cnt[i0 + 1];
      if (i0 + 2 < n) v.z = cnt[i0 + 2];
    }
    const int s1 = v.x, s2 = s1 + v.y, s3 = s2 + v.z, s4 = s3 + v.w;
    int ws = s4;
#pragma unroll
    for (int off = 1; off < 64; off <<= 1) {
      int o = __shfl_up(ws, off, 64);
      if (lane >= off) ws += o;
    }
    if (lane == 63) wsum[wid] = ws;
    __syncthreads();
    if (wid == 0) {
      int t = (lane < 16) ? wsum[lane] : 0;
#pragma unroll
      for (int off = 1; off < 16; off <<= 1) {
        int o = __shfl_up(t, off, 64);
        if (lane >= off) t += o;
      }
      if (lane < 16) wsum[lane] = t;
    }
    __syncthreads();
    const int carry = carry_sh;
    const int tbase = carry + (wid ? wsum[wid - 1] : 0) + ws - s4;  // exclusive
    if (i0     < n) { outA[i0]     = tbase;      outB[i0]     = tbase; }
    if (i0 + 1 < n) { outA[i0 + 1] = tbase + s1; outB[i0 + 1] = tbase + s1; }
    if (i0 + 2 < n) { outA[i0 + 2] = tbase + s2; outB[i0 + 2] = tbase + s2; }
    if (i0 + 3 < n) { outA[i0 + 3] = tbase + s3; outB[i0 + 3] = tbase + s3; }
    __syncthreads();
    if (tid == 0) carry_sh = carry + wsum[15];
    __syncthreads();
  }
  if (tid == 0) outA[n] = carry_sh;
}

// ---------- pass 2: partition edges into 8 contiguous group segments ----------
__global__ __launch_bounds__(256) void partition_kernel(
    const int* __restrict__ rows, const int* __restrict__ cols,
    const float* __restrict__ vals, const int* __restrict__ pofsT,
    int2* __restrict__ part, int n_edges, unsigned gmagic) {
  __shared__ int lofs[8];
  if (threadIdx.x < 8) lofs[threadIdx.x] = pofsT[threadIdx.x * NBLK + blockIdx.x];
  __syncthreads();
  for (int e = blockIdx.x * 256 + threadIdx.x; e < n_edges; e += NBLK * 256) {
    const int r = rows[e];
    const int g = grp_of(r, gmagic);
    const int slot = atomicAdd(&lofs[g], 1);
    const unsigned short hb = __half_as_ushort(__float2half_rn(vals[e] * 0.5f));
    int2 rv;
    rv.x = r;
    rv.y = (int)(((unsigned)cols[e] << 15) | ((unsigned)hb >> 1));
    part[slot] = rv;
  }
}

// ---------- pass 3: scatter within XCD-local group (write-merge friendly) ----------
__global__ __launch_bounds__(256) void scatter2_kernel(
    const int2* __restrict__ part, const int* __restrict__ pofsT,
    int* __restrict__ cursor, unsigned* __restrict__ colpack) {
  const int g  = blockIdx.x & 7;
  const int bk = blockIdx.x >> 3;
  const int nb = gridDim.x >> 3;
  const int s0 = pofsT[g * NBLK];
  const int s1 = pofsT[(g + 1) * NBLK];   // g=7 -> pofsT[8*NBLK] = total
  for (int i = s0 + bk * 256 + threadIdx.x; i < s1; i += nb * 256) {
    const int2 rv = part[i];
    const int pos = atomicAdd(&cursor[rv.x], 1);
    colpack[pos] = (unsigned)rv.y;
  }
}

// ---------- SpMM, feature-sliced for XCD L2 locality ----------
// 4 slices x 64 features (128B). slice = blockIdx&3; with bid%8 -> XCD
// round-robin, slice s runs only on XCDs {s, s+4}: per-XCD gather working
// set = 12.8 MB (vs 51.2), so L2 hit rate rises. Correctness does not
// depend on the XCD mapping. Half-wave = one node: 32 lanes x 4B = 128B.
__global__ __launch_bounds__(256) void spmm_slice(
    const unsigned short* __restrict__ hin, const int* __restrict__ row_ptr,
    const unsigned* __restrict__ colpack, unsigned short* __restrict__ hout,
    int n_nodes) {
  const int slice = blockIdx.x & 3;
  const int lane = threadIdx.x & 63;
  const int half = lane >> 5;
  const int sub  = lane & 31;
  const int wgid = ((blockIdx.x >> 2) * 256 + threadIdx.x) >> 6;  // node-pair id
  const int node = wgid * 2 + half;
  const bool ok = node < n_nodes;
  int start = 0, end = 0;
  if (ok) { start = row_ptr[node]; end = row_ptr[node + 1]; }

  const unsigned* __restrict__ hinw = reinterpret_cast<const unsigned*>(hin);
  const int fofs = slice * 32 + sub;       // uint index within a 128-uint row

  float acc0 = 0.f, acc1 = 0.f;

  for (int base = start; base < end; base += 32) {
    const int cnt = min(32, end - base);
    unsigned u = 0;                        // u=0 decodes to (col=0, val=0)
    if (base + sub < end) u = colpack[base + sub];
    for (int t = 0; t < cnt; t += 8) {
      unsigned hv[8];
      float v[8];
#pragma unroll
      for (int j = 0; j < 8; ++j) {
        const unsigned ue = (unsigned)__shfl((int)u, (half << 5) + t + j, 64);
        const int c = (int)(ue >> 15);
        v[j] = __half2float(__ushort_as_half((unsigned short)((ue & 0x7fffu) << 1)));
        hv[j] = hinw[(size_t)c * 128 + fofs];   // 8 independent 4B gathers
      }
#pragma unroll
      for (int j = 0; j < 8; ++j) {
        acc0 += v[j] * asf(hv[j] << 16);
        acc1 += v[j] * asf(hv[j] & 0xffff0000u);
      }
    }
  }
  if (ok) {
    reinterpret_cast<unsigned*>(hout)[(size_t)node * 128 + fofs] =
        (unsigned)f2bf(acc0) | ((unsigned)f2bf(acc1) << 16);
  }
}

// ---------- W[k][n] fp32 -> WT[n][k] bf16 ----------
__global__ __launch_bounds__(256) void wconv_kernel(
    const float* __restrict__ W, unsigned short* __restrict__ WT) {
  int k = blockIdx.x;
  int n = threadIdx.x;
  WT[(size_t)n * N_D + k] = f2bf(W[(size_t)k * N_D + n]);
}

// ---------- GEMM: H[M,256](bf16) @ W(256,256 via WT bf16) ----------
template <bool RELU, bool OUT_BF16>
__global__ __launch_bounds__(256) void gemm_csr(
    const unsigned short* __restrict__ H, const unsigned short* __restrict__ WT,
    void* __restrict__ C, int M) {
  const int wave = threadIdx.x >> 6;
  const int lane = threadIdx.x & 63;
  const int m = lane & 15;
  const int p = lane >> 4;
  const int row0 = blockIdx.x * 64;
  const int col0 = wave * 64;

  f32x4 acc[4][4];
#pragma unroll
  for (int i = 0; i < 4; ++i)
#pragma unroll
    for (int j = 0; j < 4; ++j) acc[i][j] = (f32x4){0.f, 0.f, 0.f, 0.f};

  for (int k0 = 0; k0 < N_D; k0 += 32) {
    bf16x8 a[4], b[4];
#pragma unroll
    for (int rt = 0; rt < 4; ++rt) {
      const int r = row0 + rt * 16 + m;
      if (r < M) {
        a[rt] = *reinterpret_cast<const bf16x8*>(H + (size_t)r * N_D + k0 + p * 8);
      } else {
        a[rt] = (bf16x8){0, 0, 0, 0, 0, 0, 0, 0};
      }
    }
#pragma unroll
    for (int nt = 0; nt < 4; ++nt) {
      b[nt] = *reinterpret_cast<const bf16x8*>(
          WT + (size_t)(col0 + nt * 16 + m) * N_D + k0 + p * 8);
    }
#pragma unroll
    for (int rt = 0; rt < 4; ++rt)
#pragma unroll
      for (int nt = 0; nt < 4; ++nt)
        acc[rt][nt] = __builtin_amdgcn_mfma_f32_16x16x32_bf16(a[rt], b[nt], acc[rt][nt], 0, 0, 0);
  }

#pragma unroll
  for (int rt = 0; rt < 4; ++rt) {
#pragma unroll
    for (int nt = 0; nt < 4; ++nt) {
      const int col = col0 + nt * 16 + m;
#pragma unroll
      for (int rr = 0; rr < 4; ++rr) {
        const int r = row0 + rt * 16 + p * 4 + rr;
        if (r < M) {
          float v = acc[rt][nt][rr];
          if (RELU) v = fmaxf(v, 0.f);
          if (OUT_BF16)
            ((unsigned short*)C)[(size_t)r * N_D + col] = f2bf(v);
          else
            ((float*)C)[(size_t)r * N_D + col] = v;
        }
      }
    }
  }
}

extern "C" void kernel_launch(void* const* d_in, const int* in_sizes, int n_in,
                              void* d_out, int out_size, void* d_ws, size_t ws_size,
                              hipStream_t stream) {
  const float* x    = (const float*)d_in[0];
  const float* vals = (const float*)d_in[1];
  const float* W0   = (const float*)d_in[2];
  const float* W1   = (const float*)d_in[3];
  const int*   rows = (const int*)d_in[4];
  const int*   cols = (const int*)d_in[5];

  const int n_edges = in_sizes[1];
  const int M = in_sizes[0] / N_D;        // 100000
  const size_t n_feat = (size_t)M * N_D;  // 25.6M elements

  char* ws = (char*)d_ws;
  unsigned short* hA      = (unsigned short*)(ws);                  // 51.2 MB bf16
  unsigned*       colpack = (unsigned*)(ws + 51200000);             // 12.8 MB
  int*            row_ptr = (int*)(ws + 64000000);                  // 400 KB
  int*            cursor  = (int*)(ws + 64400128);                  // 400 KB
  int*            cnt     = (int*)(ws + 64800256);                  // 400 KB
  int*            cntT    = (int*)(ws + 65200384);                  // 26.6 KB
  int*            pofsT   = (int*)(ws + 65227264);                  // 26.6 KB
  int*            pscr    = (int*)(ws + 65254144);                  // 26.6 KB
  unsigned short* wt      = (unsigned short*)(ws + 65281024);       // 128 KB
  // d_out (102.4 MB fp32) hosts bf16/scratch buffers until the final GEMM:
  unsigned short* hB   = (unsigned short*)d_out;                    // lower 51.2 MB
  unsigned short* xb   = (unsigned short*)d_out + n_feat;           // upper 51.2 MB
  int2*           part = (int2*)((char*)d_out + 51200000);          // 25.6 MB (dead until conv)

  const int sblocks = 4 * ((M + 7) / 8);    // 4 slices x (8 nodes per block)
  const int gblocks = (M + 63) / 64;
  const int cblocks = (int)(n_feat / 4 + 255) / 256;
  const int rpg = (M + 7) / 8;              // rows per XCD group
  const unsigned gmagic = (unsigned)(((1ULL << 37) + rpg - 1) / (unsigned long long)rpg);

  // --- CSR build (once; reused by all 4 SpMMs) ---
  hipMemsetAsync(cnt, 0, (size_t)M * sizeof(int), stream);
  count_kernel<<<NBLK, 256, 0, stream>>>(rows, cnt, cntT, n_edges, gmagic);
  scan_kernel<<<1, 1024, 0, stream>>>(cnt, row_ptr, cursor, M);
  scan_kernel<<<1, 1024, 0, stream>>>(cntT, pofsT, pscr, 8 * NBLK);
  partition_kernel<<<NBLK, 256, 0, stream>>>(rows, cols, vals, pofsT, part,
                                             n_edges, gmagic);
  scatter2_kernel<<<NBLK, 256, 0, stream>>>(part, pofsT, cursor, colpack);
  conv_kernel<<<cblocks, 256, 0, stream>>>(x, xb, (int)(n_feat / 4));  // after part is dead

  // --- layer 0 ---
  spmm_slice<<<sblocks, 256, 0, stream>>>(xb, row_ptr, colpack, hA, M);  // hA = 0.5*A x
  spmm_slice<<<sblocks, 256, 0, stream>>>(hA, row_ptr, colpack, hB, M);  // hB = 0.5*A hA
  wconv_kernel<<<N_D, N_D, 0, stream>>>(W0, wt);
  gemm_csr<true, true><<<gblocks, 256, 0, stream>>>(hB, wt, hA, M);      // hA = relu(hB@W0)

  // --- layer 1 ---
  spmm_slice<<<sblocks, 256, 0, stream>>>(hA, row_ptr, colpack, hB, M);
  spmm_slice<<<sblocks, 256, 0, stream>>>(hB, row_ptr, colpack, hA, M);
  wconv_kernel<<<N_D, N_D, 0, stream>>>(W1, wt);
  gemm_csr<false, false><<<gblocks, 256, 0, stream>>>(hA, wt, d_out, M);  // out fp32
}